// Round 12
// baseline (150.416 us; speedup 1.0000x reference)
//
#include <hip/hip_runtime.h>
#include <stdint.h>

// RGCNConv: out = sum_r ((A * [edge==r]) @ x) @ W_r + bias
// N=4096, IN=OUT=256, R=8.
//   k_prep : FUSED, role = blockIdx%3 (<2 -> k_t, ==2 -> k_y) so roles
//            co-reside on every CU from t=0.
//            k_t: transpose-pack A+et -> Apk[(jg*4096+i)] granules of 8 u16
//                 ([e:3][exp4:4][mant9]); loads software-pipelined in 4
//                 batches of 8 b128 (2-deep, named reg sets) for MLP.
//            k_y: yt[(j*256+o)*8+r] = (x@W_r)[j][o] bf16 granules.
//   k_main : expanded GEMM, step = 1 jg (8 j = K_eff 64). A coalesced b128
//            global->reg; B via global_load_lds 3-deep; 6 VMEM/thread/step,
//            honest vmcnt(6), 1 barrier/step; kz->XCD pinned grid (b&15=kz,
//            XCD = b%8) keeps each kz's yt window + Apk slice in one L2.
//   k_red  : sum 16 f16 partials + bias.
// ws: yt 16MB @0, Apk 32MB @16MB, partials f16 32MB @48MB (=80MB).

#define NN 4096

typedef __attribute__((ext_vector_type(8)))  short s16x8;   // 8 bf16 MFMA frag
typedef __attribute__((ext_vector_type(16))) float f32x16;  // 32x32 C/D
typedef __attribute__((ext_vector_type(4)))  float fx4;
typedef __attribute__((ext_vector_type(4)))  int   ix4;
typedef __attribute__((ext_vector_type(4)))  unsigned int ux4;
typedef __attribute__((ext_vector_type(4)))  _Float16 h4;

union uq { ux4 u; s16x8 s; };

__device__ __forceinline__ unsigned short f2bf(float f) {
  union { float f; unsigned int u; } v; v.f = f;
  unsigned int r = v.u + 0x7fffu + ((v.u >> 16) & 1u);  // RNE
  return (unsigned short)(r >> 16);
}

__device__ __forceinline__ void gld16(const void* g, void* l) {
  __builtin_amdgcn_global_load_lds(
      (const __attribute__((address_space(1))) unsigned int*)(uintptr_t)g,
      (__attribute__((address_space(3))) unsigned int*)(uintptr_t)l, 16, 0, 0);
}

// pack (a in [0,1), e in 0..7) -> u16 [e:3][exp4:4][mant9]
__device__ __forceinline__ unsigned packAE(float a, int e) {
  unsigned ab = __float_as_uint(a) + 0x2000u;   // round mant9 (carry-safe)
  unsigned ex = ab >> 23;
  int el = (int)ex - 112;                       // 1..15 valid
  unsigned m9 = (ab >> 14) & 0x1FFu;
  unsigned v = ((unsigned)el << 9) | m9;
  if (el <= 0) v = 0;                           // tiny -> 0 (neg err ~6e-5)
  return (unsigned short)(((unsigned)e << 13) | (v & 0x1FFFu));
}

// ---------------- init (atomic fallback path only) ----------------
__global__ void k_init(const float* __restrict__ bias, float* __restrict__ out) {
  int idx = blockIdx.x * 256 + threadIdx.x;
  out[idx] = bias[idx & 255];
}

// ---------------- k_prep: fused transpose-pack + y-GEMM ----------------
__global__ __launch_bounds__(256, 2) void k_prep(const float* __restrict__ A,
                                                 const int*   __restrict__ et,
                                                 unsigned short* __restrict__ Apk,
                                                 const float* __restrict__ x,
                                                 const float* __restrict__ W,
                                                 unsigned short* __restrict__ yt) {
  __shared__ char smraw[65536];  // k_t: 33KB u32[64*129]; k_y: 64KB u16
  const int t = threadIdx.x;
  const int b = blockIdx.x;
  const int rm = b % 3;

  if (rm < 2) {
    // ---- k_t role: tile 32 i x 512 j; bt = 0..1023 ----
    unsigned int* lds = (unsigned int*)smraw;   // [64 jg][129 dwords] (pad)
    const int bt = (b / 3) * 2 + rm;
    const int ib = (bt & 127) * 32;
    const int byy = bt >> 7;
    const int jb = byy * 512;
    const int jgb = byy * 64;

    const int jl = (t & 127) * 4;
    const int r0 = t >> 7;
    const int jg = jl >> 3;
    const int dd = (jl & 7) >> 1;               // 0 or 2
    const float* baseA = A  + (size_t)(ib + r0) * NN + jb + jl;
    const int*   baseE = et + (size_t)(ib + r0) * NN + jb + jl;

#define LOADB(g, AA, EE) do {                                             \
    _Pragma("unroll")                                                     \
    for (int k = 0; k < 4; ++k) {                                         \
      AA[k] = *(const fx4*)(baseA + (size_t)((g) * 8 + k * 2) * NN);      \
      EE[k] = *(const ix4*)(baseE + (size_t)((g) * 8 + k * 2) * NN);      \
    }                                                                     \
  } while (0)

#define PROCB(g, AA, EE) do {                                             \
    _Pragma("unroll")                                                     \
    for (int k = 0; k < 4; ++k) {                                         \
      const int row = ((g) * 4 + k) * 2 + r0;                             \
      unsigned d0 = (unsigned)packAE(AA[k].x, EE[k].x)                    \
                  | ((unsigned)packAE(AA[k].y, EE[k].y) << 16);           \
      unsigned d1 = (unsigned)packAE(AA[k].z, EE[k].z)                    \
                  | ((unsigned)packAE(AA[k].w, EE[k].w) << 16);           \
      lds[jg * 129 + row * 4 + dd]     = d0;                              \
      lds[jg * 129 + row * 4 + dd + 1] = d1;                              \
    }                                                                     \
  } while (0)

    fx4 aP[4], aQ[4]; ix4 eP[4], eQ[4];
    LOADB(0, aP, eP);
    LOADB(1, aQ, eQ);
    PROCB(0, aP, eP);
    LOADB(2, aP, eP);
    PROCB(1, aQ, eQ);
    LOADB(3, aQ, eQ);
    PROCB(2, aP, eP);
    PROCB(3, aQ, eQ);
#undef LOADB
#undef PROCB
    __syncthreads();

    const int lh1 = (t >> 5) & 1, l31 = t & 31;
    const int wv = t >> 6;
#pragma unroll
    for (int v = 0; v < 8; ++v) {
      const int jgw = (wv * 8 + v) * 2 + lh1;   // 0..63
      const int base = jgw * 129 + l31 * 4;
      ux4 q;
      q.x = lds[base]; q.y = lds[base + 1]; q.z = lds[base + 2]; q.w = lds[base + 3];
      ((ux4*)Apk)[(size_t)(jgb + jgw) * NN + ib + l31] = q;
    }
    return;
  }

  // ---- k_y role: b2 = 0..511 ----
  unsigned short* Wl = (unsigned short*)smraw;  // [128 n'][256 k]
  const int b2 = b / 3;
  const int j0 = (b2 & 31) * 128;
  const int o0 = (b2 >> 5) * 16;

  {
    const int r = t >> 5, kc = t & 31;
#pragma unroll
    for (int u = 0; u < 8; ++u) {
      const int k = kc * 8 + u;
      const fx4* wp = (const fx4*)(W + ((size_t)r * 256 + k) * 256 + o0);
      fx4 w[4] = { wp[0], wp[1], wp[2], wp[3] };
#pragma unroll
      for (int i = 0; i < 16; ++i) {
        const int row = i * 8 + r;
        const int gs  = (k >> 3) ^ (row & 7);
        Wl[row * 256 + gs * 8 + (k & 7)] = f2bf(w[i >> 2][i & 3]);
      }
    }
  }
  __syncthreads();

  const int lane = t & 63, wid = t >> 6;
  const int l15 = lane & 15, lh = lane >> 4;
  const int npb = wid * 32;

  fx4 acc[8][2];
#pragma unroll
  for (int m = 0; m < 8; ++m)
#pragma unroll
    for (int n = 0; n < 2; ++n) acc[m][n] = 0.f;

  unsigned int qb[2];
#pragma unroll
  for (int n = 0; n < 2; ++n) {
    int row = npb + n * 16 + l15;
    qb[n] = (unsigned)(row * 512 + 16 * (lh ^ (row & 3))) ^ (64u * ((row >> 2) & 1));
  }
  const char* WlB = (const char*)Wl;
  const float* xb = x + (size_t)(j0 + l15) * 256 + lh * 8;

#pragma unroll
  for (int ks = 0; ks < 8; ++ks) {
    s16x8 a[8];
#pragma unroll
    for (int m = 0; m < 8; ++m) {
      const fx4* xp = (const fx4*)(xb + (size_t)m * 16 * 256 + ks * 32);
      fx4 x0 = xp[0], x1 = xp[1];
      s16x8 av;
#pragma unroll
      for (int i = 0; i < 4; ++i) av[i] = (short)f2bf(x0[i]);
#pragma unroll
      for (int i = 0; i < 4; ++i) av[4 + i] = (short)f2bf(x1[i]);
      a[m] = av;
    }
#pragma unroll
    for (int n = 0; n < 2; ++n) {
      s16x8 bb = *(const s16x8*)(WlB + (qb[n] ^ (unsigned)(ks * 64)));
#pragma unroll
      for (int m = 0; m < 8; ++m)
        acc[m][n] = __builtin_amdgcn_mfma_f32_16x16x32_bf16(a[m], bb, acc[m][n], 0, 0, 0);
    }
  }

#pragma unroll
  for (int m = 0; m < 8; ++m)
#pragma unroll
    for (int n = 0; n < 2; ++n)
#pragma unroll
      for (int q = 0; q < 4; ++q) {
        int jl = m * 16 + lh * 4 + q;
        int np = npb + n * 16 + l15;
        int o  = o0 + (np >> 3);
        yt[((size_t)(j0 + jl) * 256 + o) * 8 + (np & 7)] = f2bf(acc[m][n][q]);
      }
}

// ---------------- k_main ----------------
// 1-D grid 1024: b = io*16 + kz (kz = b&15 -> XCD = b%8: kz's yt window +
// Apk slice pinned to one L2). io: i0 = (io>>1)*128, o0 = (io&1)*128.
// Block 128x128, 4 waves (2i x 2o), wave tile 64x64 (m2 x n2 32x32x16).
// Step = 1 jg (8 j, K_eff 64). A: coalesced b128/lane from Apk.
// B: LDS 3 x 16KB via gld16, linear. 6 VMEM/thread/step; vmcnt(6); 1 barrier.
__global__ __launch_bounds__(256, 3) void k_main(const unsigned short* __restrict__ Apk,
                                                 const unsigned short* __restrict__ yt,
                                                 float* __restrict__ dstF,
                                                 _Float16* __restrict__ dstH,
                                                 int usePart) {
  __shared__ ux4 Bl[3 * 1024];  // 48 KB
  char* Bc = (char*)Bl;
  const int t = threadIdx.x, lane = t & 63, w = t >> 6;
  const int l31 = lane & 31, lh1 = lane >> 5;
  const int wm = w >> 1, wn = w & 1;
  const int b = blockIdx.x;
  const int kz = b & 15;
  const int io = b >> 4;
  const int i0 = (io >> 1) * 128;
  const int o0 = (io & 1) * 128;
  const int jb = kz * 256;          // j-window 256 = 32 jg-steps
  const int jg0 = kz * 32;

  const ux4* pA[2];
#pragma unroll
  for (int m = 0; m < 2; ++m)
    pA[m] = (const ux4*)Apk + (size_t)jg0 * NN + i0 + wm * 64 + m * 32 + l31;

  const ux4* ytg = (const ux4*)yt;
  const ux4* pB[4];
  unsigned dOff[4];
#pragma unroll
  for (int u = 0; u < 4; ++u) {
    int slot = u * 256 + t;
    pB[u] = ytg + (size_t)(jb + (slot >> 7)) * 256 + o0 + (slot & 127);
    dOff[u] = (unsigned)(slot * 16);
  }

#define ISSUE(sq, bb, ASET) do {                                          \
    _Pragma("unroll")                                                     \
    for (int u = 0; u < 4; ++u)                                           \
      gld16(pB[u] + (size_t)(sq) * 2048, Bc + (bb) * 16384 + dOff[u]);    \
    ASET[0] = pA[0][(size_t)(sq) * NN];                                   \
    ASET[1] = pA[1][(size_t)(sq) * NN];                                   \
  } while (0)

  const unsigned shA = (unsigned)(lh1 * 16);
#define BUILD(ASET, FR) do {                                              \
    _Pragma("unroll")                                                     \
    for (int m = 0; m < 2; ++m)                                           \
      _Pragma("unroll")                                                   \
      for (int ks = 0; ks < 4; ++ks) {                                    \
        unsigned u16 = (ASET[m][ks] >> shA) & 0xFFFFu;                    \
        unsigned a16 = 0x3800u | ((u16 >> 2) & 0x7FFu);                   \
        unsigned e   = u16 >> 13;                                         \
        unsigned long long sh = (unsigned long long)a16 << ((e & 3u) << 4); \
        unsigned lo = (unsigned)sh, hi = (unsigned)(sh >> 32);            \
        bool c = e < 4;                                                   \
        ux4 q; q.x = c ? lo : 0u; q.y = c ? hi : 0u;                      \
        q.z = c ? 0u : lo; q.w = c ? 0u : hi;                             \
        FR[m][ks].u = q;                                                  \
      }                                                                   \
  } while (0)

  unsigned rB[2];
#pragma unroll
  for (int n = 0; n < 2; ++n)
    rB[n] = (unsigned)((wn * 64 + n * 32 + l31) * 16);

#define COMPUTE(bb, FR) do {                                              \
    const unsigned base = (unsigned)((bb) * 16384) + (unsigned)(lh1 * 2048); \
    _Pragma("unroll")                                                     \
    for (int ks = 0; ks < 4; ++ks) {                                      \
      uq b0, b1;                                                          \
      b0.u = *(const ux4*)(Bc + base + (unsigned)(ks * 4096) + rB[0]);    \
      b1.u = *(const ux4*)(Bc + base + (unsigned)(ks * 4096) + rB[1]);    \
      _Pragma("unroll")                                                   \
      for (int m = 0; m < 2; ++m) {                                       \
        acc[m][0] = __builtin_amdgcn_mfma_f32_32x32x16_bf16(FR[m][ks].s, b0.s, acc[m][0], 0, 0, 0); \
        acc[m][1] = __builtin_amdgcn_mfma_f32_32x32x16_bf16(FR[m][ks].s, b1.s, acc[m][1], 0, 0, 0); \
      }                                                                   \
    }                                                                     \
  } while (0)

  f32x16 acc[2][2];
#pragma unroll
  for (int m = 0; m < 2; ++m)
#pragma unroll
    for (int n = 0; n < 2; ++n) acc[m][n] = 0.f;

  ux4 aE[2], aO[2];
  uq frE[2][4], frO[2][4];

  ISSUE(0, 0, aE);
  ISSUE(1, 1, aO);

  for (int s = 0; s < 32; s += 2) {
    const int sq2 = (s + 2 < 32) ? s + 2 : 31;
    const int sq3 = (s + 3 < 32) ? s + 3 : 31;
    const int b0 = s % 3, b1 = (s + 1) % 3, b2 = (s + 2) % 3;
    // even step s
    asm volatile("s_waitcnt vmcnt(6)" ::: "memory");
    __builtin_amdgcn_s_barrier();
    BUILD(aE, frE);
    ISSUE(sq2, b2, aE);
    __builtin_amdgcn_s_setprio(1);
    COMPUTE(b0, frE);
    __builtin_amdgcn_s_setprio(0);
    // odd step s+1
    asm volatile("s_waitcnt vmcnt(6)" ::: "memory");
    __builtin_amdgcn_s_barrier();
    BUILD(aO, frO);
    ISSUE(sq3, b0, aO);
    __builtin_amdgcn_s_setprio(1);
    COMPUTE(b1, frO);
    __builtin_amdgcn_s_setprio(0);
  }
  asm volatile("s_waitcnt vmcnt(0)" ::: "memory");  // drain before exit

  // epilogue. 32x32 C layout: col = l31, row = (q&3) + 8*(q>>2) + 4*lh1
  if (usePart) {
    _Float16* pp = dstH + ((size_t)kz << 20);
#pragma unroll
    for (int m = 0; m < 2; ++m)
#pragma unroll
      for (int n = 0; n < 2; ++n)
#pragma unroll
        for (int q = 0; q < 16; ++q) {
          int gi = i0 + wm * 64 + m * 32 + (q & 3) + 8 * (q >> 2) + 4 * lh1;
          int go = o0 + wn * 64 + n * 32 + l31;
          pp[(size_t)gi * 256 + go] = (_Float16)acc[m][n][q];
        }
  } else {
#pragma unroll
    for (int m = 0; m < 2; ++m)
#pragma unroll
      for (int n = 0; n < 2; ++n)
#pragma unroll
        for (int q = 0; q < 16; ++q) {
          int gi = i0 + wm * 64 + m * 32 + (q & 3) + 8 * (q >> 2) + 4 * lh1;
          int go = o0 + wn * 64 + n * 32 + l31;
          atomicAdd(dstF + (size_t)gi * 256 + go, acc[m][n][q]);
        }
  }
#undef ISSUE
#undef BUILD
#undef COMPUTE
}

// ---------------- k_red: sum 16 f16 partials + bias -> out ----------------
__global__ __launch_bounds__(256) void k_red(const _Float16* __restrict__ part,
                                             const float* __restrict__ bias,
                                             float* __restrict__ out) {
  int idx = blockIdx.x * 256 + threadIdx.x;     // 262144 fx4-groups
  fx4 s = *(const fx4*)(bias + ((idx << 2) & 255));
#pragma unroll
  for (int k = 0; k < 16; ++k) {
    h4 h = *(const h4*)(part + ((size_t)k << 20) + (size_t)idx * 4);
    s.x += (float)h.x; s.y += (float)h.y; s.z += (float)h.z; s.w += (float)h.w;
  }
  ((fx4*)out)[idx] = s;
}

extern "C" void kernel_launch(void* const* d_in, const int* in_sizes, int n_in,
                              void* d_out, int out_size, void* d_ws, size_t ws_size,
                              hipStream_t stream) {
  const float* x    = (const float*)d_in[0];
  const float* A    = (const float*)d_in[1];
  const int*   et   = (const int*)d_in[2];
  const float* W    = (const float*)d_in[3];
  const float* bias = (const float*)d_in[4];
  float* out = (float*)d_out;

  unsigned short* yt  = (unsigned short*)d_ws;                               // 16 MB
  unsigned short* Apk = (unsigned short*)((char*)d_ws + ((size_t)16 << 20)); // 32 MB
  _Float16*       pp  = (_Float16*)((char*)d_ws + ((size_t)48 << 20));       // 32 MB

  const bool usePart = ws_size >= ((size_t)80 << 20);

  k_prep<<<dim3(1536), dim3(256), 0, stream>>>(A, et, Apk, x, W, yt);
  if (usePart) {
    k_main<<<dim3(1024), dim3(256), 0, stream>>>(Apk, yt, out, pp, 1);
    k_red<<<dim3(1024), dim3(256), 0, stream>>>(pp, bias, out);
  } else {
    k_init<<<dim3(4096), dim3(256), 0, stream>>>(bias, out);
    k_main<<<dim3(1024), dim3(256), 0, stream>>>(Apk, yt, out, pp, 0);
  }
}